// Round 3
// baseline (93.855 us; speedup 1.0000x reference)
//
#include <hip/hip_runtime.h>
#include <hip/hip_bf16.h>

#define BB 8
#define NN 2048
#define FD 128

typedef float f32x4 __attribute__((ext_vector_type(4)));
typedef short bf16x8 __attribute__((ext_vector_type(8)));
typedef short s16x4 __attribute__((ext_vector_type(4)));

__device__ __forceinline__ short f2bf(float f) {
  union { __hip_bfloat16 h; short s; } u;
  u.h = __float2bfloat16(f);
  return u.s;
}

// ---------------- kernel 1: fused degree + XW + pack ----------------
// Phase A: streaming rowsums of this block's 64 adj rows -> r
// Phase B: XWs = r[m] * (X @ W); writes fp32 row-major xwsr and bf16
//          MFMA-B-fragment-packed bpack: elem (m,o) -> (m>>3)*1024 + o*8 + (m&7)
__global__ __launch_bounds__(256) void k_xw_fused(const float* __restrict__ X,
                                                  const float* __restrict__ adj,
                                                  const float* __restrict__ W,
                                                  short* __restrict__ bpack,
                                                  float* __restrict__ xwsr,
                                                  float* __restrict__ r) {
  __shared__ __align__(16) float Xs[64][132];
  __shared__ __align__(16) float Ws[128][128];
  __shared__ float Ls[64];
  const int b    = blockIdx.y;
  const int m0   = blockIdx.x * 64;
  const int t    = threadIdx.x;
  const int lane = t & 63;
  const int w    = t >> 6;

  // ---- T14: issue X/W staging loads early, commit to LDS after phase A ----
  f32x4 wreg[16], xreg[8];
  {
    const f32x4* wp = reinterpret_cast<const f32x4*>(W);
#pragma unroll
    for (int i = 0; i < 16; ++i) wreg[i] = wp[t + 256 * i];
    const f32x4* xp = reinterpret_cast<const f32x4*>(X + ((size_t)b * NN + m0) * FD);
#pragma unroll
    for (int i = 0; i < 8; ++i) xreg[i] = xp[t + 256 * i];
  }

  // ---- phase A: streaming degree rowsums (wave w owns 16 rows) ----
  {
    float s[16];
#pragma unroll
    for (int rr = 0; rr < 16; ++rr) s[rr] = 0.f;
    const float* base = adj + ((size_t)b * NN + m0 + w * 16) * NN;
#pragma unroll
    for (int rr = 0; rr < 16; ++rr) {
      const f32x4* p = reinterpret_cast<const f32x4*>(base + (size_t)rr * NN);
#pragma unroll
      for (int i = 0; i < 8; ++i) {
        f32x4 v = p[lane + 64 * i];
        s[rr] += (v.x + v.y) + (v.z + v.w);
      }
    }
#pragma unroll
    for (int rr = 0; rr < 16; ++rr) {
      float v = s[rr];
#pragma unroll
      for (int off = 32; off >= 1; off >>= 1) v += __shfl_xor(v, off, 64);
      if (lane == 0) {
        float rv = rsqrtf(1.0f + v);
        Ls[w * 16 + rr] = rv;
        r[b * NN + m0 + w * 16 + rr] = rv;
      }
    }
  }
  // ---- commit staged X, W to LDS ----
  {
    f32x4* wd = reinterpret_cast<f32x4*>(&Ws[0][0]);
#pragma unroll
    for (int i = 0; i < 16; ++i) wd[t + 256 * i] = wreg[i];
#pragma unroll
    for (int i = 0; i < 8; ++i) {
      int slot = t + 256 * i;
      *reinterpret_cast<f32x4*>(&Xs[slot >> 5][(slot & 31) * 4]) = xreg[i];
    }
  }
  __syncthreads();

  // ---- phase B: 64x128 fp32 GEMM, scale rows by r, pack outputs ----
  const int ot = (t & 15) * 8;
  const int mt = (t >> 4) * 4;
  float acc[4][8];
#pragma unroll
  for (int i = 0; i < 4; ++i)
#pragma unroll
    for (int j = 0; j < 8; ++j) acc[i][j] = 0.f;

  for (int k = 0; k < 128; k += 4) {
    f32x4 xv[4];
#pragma unroll
    for (int i = 0; i < 4; ++i) xv[i] = *reinterpret_cast<const f32x4*>(&Xs[mt + i][k]);
#pragma unroll
    for (int kk = 0; kk < 4; ++kk) {
      float wv[8];
#pragma unroll
      for (int j = 0; j < 8; ++j) wv[j] = Ws[k + kk][ot + j];
#pragma unroll
      for (int i = 0; i < 4; ++i)
#pragma unroll
        for (int j = 0; j < 8; ++j) acc[i][j] = fmaf(xv[i][kk], wv[j], acc[i][j]);
    }
  }
  const int bm = b * NN + m0 + mt;
#pragma unroll
  for (int i = 0; i < 4; ++i) {
    float rm = Ls[mt + i];
#pragma unroll
    for (int j = 0; j < 8; ++j) acc[i][j] *= rm;
  }
#pragma unroll
  for (int i = 0; i < 4; ++i) {
    f32x4 lo = {acc[i][0], acc[i][1], acc[i][2], acc[i][3]};
    f32x4 hi = {acc[i][4], acc[i][5], acc[i][6], acc[i][7]};
    float* dst = xwsr + (size_t)(bm + i) * FD + ot;
    *reinterpret_cast<f32x4*>(dst) = lo;
    *reinterpret_cast<f32x4*>(dst + 4) = hi;
  }
  short* bp = bpack + (size_t)b * NN * FD;
  const int grp = (m0 + mt) >> 3;
  const int h   = ((m0 + mt) >> 2) & 1;
#pragma unroll
  for (int j = 0; j < 8; ++j) {
    s16x4 sv;
#pragma unroll
    for (int i = 0; i < 4; ++i) sv[i] = f2bf(acc[i][j]);
    *reinterpret_cast<s16x4*>(bp + (size_t)grp * 1024 + (ot + j) * 8 + h * 4) = sv;
  }
}

// ---------------- kernel 2: LDS-free MFMA GEMM, K-split waves ----------------
// out = leaky(r[n] * ((adj @ bpack) + xwsr[n]) + bias)
// Block = 32 rows, 4 waves: wave (strip = w&1, khalf = w>>1). Each wave does
// 16 rows x 128 cols over half the K range (1024). A-frags direct from global
// fp32 (cvt to bf16 in-reg), 4-deep prefetch; B-frags from L2 bpack, 2-deep.
// khalf=1 partials reduced into khalf=0 accs via LDS, single barrier.
__global__ __launch_bounds__(256) void k_gemm2(const float* __restrict__ adj,
                                               const short* __restrict__ bpack,
                                               const float* __restrict__ xwsr,
                                               const float* __restrict__ r,
                                               const float* __restrict__ bias,
                                               float* __restrict__ out) {
  __shared__ float Red[2][16][128];  // 16 KB
  const int b     = blockIdx.y;
  const int n0    = blockIdx.x * 32;
  const int t     = threadIdx.x;
  const int lane  = t & 63;
  const int w     = t >> 6;
  const int strip = w & 1;
  const int khalf = w >> 1;
  const int rowb  = n0 + strip * 16;

  const float* ap  = adj + ((size_t)b * NN + rowb + (lane & 15)) * NN + khalf * 1024 + (lane >> 4) * 8;
  const short* bpb = bpack + (size_t)b * NN * FD + (size_t)(khalf * 128 + (lane >> 4)) * 1024 + (lane & 15) * 8;

  f32x4 acc[8];
#pragma unroll
  for (int i = 0; i < 8; ++i) acc[i] = (f32x4){0.f, 0.f, 0.f, 0.f};

  f32x4 aS[4][2];
  bf16x8 bS[2][8];

  auto loadA = [&](int ks, f32x4 (&d)[2]) {
    const f32x4* q = reinterpret_cast<const f32x4*>(ap + ks * 32);
    d[0] = q[0];
    d[1] = q[1];
  };
  auto loadB = [&](int ks, bf16x8 (&d)[8]) {
    const short* p = bpb + (size_t)ks * 4096;
#pragma unroll
    for (int ct = 0; ct < 8; ++ct)
      d[ct] = *reinterpret_cast<const bf16x8*>(p + ct * 128);
  };
  auto step = [&](f32x4 (&sa)[2], bf16x8 (&sb)[8]) {
    bf16x8 af;
#pragma unroll
    for (int i = 0; i < 4; ++i) { af[i] = f2bf(sa[0][i]); af[4 + i] = f2bf(sa[1][i]); }
    __builtin_amdgcn_s_setprio(1);
#pragma unroll
    for (int ct = 0; ct < 8; ++ct)
      acc[ct] = __builtin_amdgcn_mfma_f32_16x16x32_bf16(af, sb[ct], acc[ct], 0, 0, 0);
    __builtin_amdgcn_s_setprio(0);
  };

  loadA(0, aS[0]); loadA(1, aS[1]); loadA(2, aS[2]); loadA(3, aS[3]);
  loadB(0, bS[0]); loadB(1, bS[1]);
#pragma unroll
  for (int ks = 0; ks < 32; ++ks) {
    step(aS[ks & 3], bS[ks & 1]);
    if (ks + 4 < 32) loadA(ks + 4, aS[ks & 3]);
    if (ks + 2 < 32) loadB(ks + 2, bS[ks & 1]);
  }

  // ---- cross-wave K reduction + fused epilogue ----
  // C/D layout: col = lane&15, row = (lane>>4)*4 + reg
  const int col = lane & 15, rq = lane >> 4;
  if (khalf == 1) {
#pragma unroll
    for (int reg = 0; reg < 4; ++reg)
#pragma unroll
      for (int ct = 0; ct < 8; ++ct)
        Red[strip][rq * 4 + reg][ct * 16 + col] = acc[ct][reg];
  }
  __syncthreads();
  if (khalf == 0) {
    const float* xr = xwsr + ((size_t)b * NN + rowb) * FD;
    float* ob = out + ((size_t)b * NN + rowb) * FD;
#pragma unroll
    for (int reg = 0; reg < 4; ++reg) {
      const int rloc = rq * 4 + reg;
      const float rn = r[b * NN + rowb + rloc];
#pragma unroll
      for (int ct = 0; ct < 8; ++ct) {
        const int o = ct * 16 + col;
        float v = acc[ct][reg] + Red[strip][rloc][o] + xr[(size_t)rloc * FD + o];
        v = rn * v + bias[o];
        ob[(size_t)rloc * FD + o] = v > 0.f ? v : 0.01f * v;
      }
    }
  }
}

extern "C" void kernel_launch(void* const* d_in, const int* in_sizes, int n_in,
                              void* d_out, int out_size, void* d_ws, size_t ws_size,
                              hipStream_t stream) {
  (void)in_sizes; (void)n_in; (void)out_size; (void)ws_size;
  const float* X    = (const float*)d_in[0];
  const float* adj  = (const float*)d_in[1];
  const float* W    = (const float*)d_in[2];
  const float* bias = (const float*)d_in[3];
  float* out = (float*)d_out;

  char* ws = (char*)d_ws;
  float* r     = (float*)ws;                                      // 64 KB
  short* bpack = (short*)(ws + 65536);                            // 4 MB
  float* xwsr  = (float*)(ws + 65536 + (size_t)BB * NN * FD * 2); // 8 MB

  k_xw_fused<<<dim3(NN / 64, BB), dim3(256), 0, stream>>>(X, adj, W, bpack, xwsr, r);
  k_gemm2<<<dim3(NN / 32, BB), dim3(256), 0, stream>>>(adj, bpack, xwsr, r, bias, out);
}

// Round 4
// 76.354 us; speedup vs baseline: 1.2292x; 1.2292x over previous
//
#include <hip/hip_runtime.h>
#include <hip/hip_bf16.h>

#define BB 8
#define NN 2048
#define FD 128

typedef float f32x4 __attribute__((ext_vector_type(4)));
typedef short bf16x8 __attribute__((ext_vector_type(8)));
typedef short s16x4 __attribute__((ext_vector_type(4)));

__device__ __forceinline__ short f2bf(float f) {
  union { __hip_bfloat16 h; short s; } u;
  u.h = __float2bfloat16(f);
  return u.s;
}

// ---------------- kernel 1: degree + bf16 A-fragment pack ----------------
// Block = 16 rows, 4 waves; wave w owns k-quarter [w*512, w*512+512).
// Streams adj fp32 once: accumulates row sums AND writes bf16 apack tiles.
// apack tile (rt, kt) = 16 rows x 32 k, 1 KB, lane-linear in the exact
// MFMA A-fragment order the gemm reads: off = kg*256B + row*16B.
__global__ __launch_bounds__(256) void k_degpack(const float* __restrict__ adj,
                                                 short* __restrict__ apack,
                                                 float* __restrict__ r) {
  __shared__ float Ls[4][16];
  const int b    = blockIdx.x >> 7;   // 128 row-tiles per batch
  const int rt   = blockIdx.x & 127;
  const int t    = threadIdx.x;
  const int lane = t & 63;
  const int w    = t >> 6;
  const int row  = (lane & 15);
  const int kg   = lane >> 4;

  const float* ap = adj + ((size_t)b * NN + rt * 16 + row) * NN + w * 512 + kg * 8;
  short* op = apack + ((size_t)(b * 128 + rt) * 64 + w * 16) * 512 + kg * 128 + row * 8;

  float s = 0.f;
#pragma unroll
  for (int kt = 0; kt < 16; ++kt) {
    const f32x4* p = reinterpret_cast<const f32x4*>(ap + kt * 32);
    f32x4 v0 = p[0], v1 = p[1];
    s += ((v0.x + v0.y) + (v0.z + v0.w)) + ((v1.x + v1.y) + (v1.z + v1.w));
    bf16x8 o;
#pragma unroll
    for (int i = 0; i < 4; ++i) { o[i] = f2bf(v0[i]); o[4 + i] = f2bf(v1[i]); }
    *reinterpret_cast<bf16x8*>(op + kt * 512) = o;
  }
  // reduce across the 4 kg groups (lanes sharing lane&15)
  s += __shfl_xor(s, 16, 64);
  s += __shfl_xor(s, 32, 64);
  if (lane < 16) Ls[w][lane] = s;
  __syncthreads();
  if (t < 16) {
    float tot = (Ls[0][t] + Ls[1][t]) + (Ls[2][t] + Ls[3][t]);
    r[b * NN + rt * 16 + t] = rsqrtf(1.0f + tot);
  }
}

// ---------------- kernel 2: XWs = r[m] * (X @ W), pack B-fragments ----------
// bpack: elem (m,o) -> (m>>3)*1024 + o*8 + (m&7); xwsr fp32 row-major.
__global__ __launch_bounds__(256) void k_xw(const float* __restrict__ X,
                                            const float* __restrict__ W,
                                            const float* __restrict__ r,
                                            short* __restrict__ bpack,
                                            float* __restrict__ xwsr) {
  __shared__ __align__(16) float Xs[64][132];
  __shared__ __align__(16) float Ws[128][128];
  const int b  = blockIdx.y;
  const int m0 = blockIdx.x * 64;
  const int t  = threadIdx.x;
  {
    const f32x4* wp = reinterpret_cast<const f32x4*>(W);
    f32x4* wd = reinterpret_cast<f32x4*>(&Ws[0][0]);
#pragma unroll
    for (int i = 0; i < 16; ++i) wd[t + 256 * i] = wp[t + 256 * i];
    const f32x4* xp = reinterpret_cast<const f32x4*>(X + ((size_t)b * NN + m0) * FD);
#pragma unroll
    for (int i = 0; i < 8; ++i) {
      int slot = t + 256 * i;
      f32x4 v = xp[slot];
      *reinterpret_cast<f32x4*>(&Xs[slot >> 5][(slot & 31) * 4]) = v;
    }
  }
  __syncthreads();
  const int ot = (t & 15) * 8;
  const int mt = (t >> 4) * 4;
  float acc[4][8];
#pragma unroll
  for (int i = 0; i < 4; ++i)
#pragma unroll
    for (int j = 0; j < 8; ++j) acc[i][j] = 0.f;

  for (int k = 0; k < 128; k += 4) {
    f32x4 xv[4];
#pragma unroll
    for (int i = 0; i < 4; ++i) xv[i] = *reinterpret_cast<const f32x4*>(&Xs[mt + i][k]);
#pragma unroll
    for (int kk = 0; kk < 4; ++kk) {
      float wv[8];
#pragma unroll
      for (int j = 0; j < 8; ++j) wv[j] = Ws[k + kk][ot + j];
#pragma unroll
      for (int i = 0; i < 4; ++i)
#pragma unroll
        for (int j = 0; j < 8; ++j) acc[i][j] = fmaf(xv[i][kk], wv[j], acc[i][j]);
    }
  }
  const int bm = b * NN + m0 + mt;
#pragma unroll
  for (int i = 0; i < 4; ++i) {
    float rm = r[bm + i];
#pragma unroll
    for (int j = 0; j < 8; ++j) acc[i][j] *= rm;
  }
#pragma unroll
  for (int i = 0; i < 4; ++i) {
    f32x4 lo = {acc[i][0], acc[i][1], acc[i][2], acc[i][3]};
    f32x4 hi = {acc[i][4], acc[i][5], acc[i][6], acc[i][7]};
    float* dst = xwsr + (size_t)(bm + i) * FD + ot;
    *reinterpret_cast<f32x4*>(dst) = lo;
    *reinterpret_cast<f32x4*>(dst + 4) = hi;
  }
  short* bp = bpack + (size_t)b * NN * FD;
  const int grp = (m0 + mt) >> 3;
  const int h   = ((m0 + mt) >> 2) & 1;
#pragma unroll
  for (int j = 0; j < 8; ++j) {
    s16x4 sv;
#pragma unroll
    for (int i = 0; i < 4; ++i) sv[i] = f2bf(acc[i][j]);
    *reinterpret_cast<s16x4*>(bp + (size_t)grp * 1024 + (ot + j) * 8 + h * 4) = sv;
  }
}

// ---------------- kernel 3: bf16 MFMA GEMM from packed operands -------------
// out = leaky(r[n] * ((adj @ XWs) + XWs[n]) + bias)
// Block = 32 rows, 4 waves: (strip = w&1, khalf = w>>1). A-frags: single
// bf16x8 loads from L3-resident apack (no cvt). B-frags from L2 bpack.
// khalf=1 partials reduced into khalf=0 via padded LDS, one barrier.
__global__ __launch_bounds__(256) void k_gemm3(const short* __restrict__ apack,
                                               const short* __restrict__ bpack,
                                               const float* __restrict__ xwsr,
                                               const float* __restrict__ r,
                                               const float* __restrict__ bias,
                                               float* __restrict__ out) {
  __shared__ float Red[2][16][132];
  const int b     = blockIdx.y;
  const int rt3   = blockIdx.x;        // 32-row tile
  const int t     = threadIdx.x;
  const int lane  = t & 63;
  const int w     = t >> 6;
  const int strip = w & 1;
  const int khalf = w >> 1;
  const int rowb  = rt3 * 32 + strip * 16;

  const short* apb = apack + ((size_t)(b * 128 + rt3 * 2 + strip) * 64 + khalf * 32) * 512
                   + (lane >> 4) * 128 + (lane & 15) * 8;
  const short* bpb = bpack + (size_t)b * NN * FD
                   + (size_t)(khalf * 128 + (lane >> 4)) * 1024 + (lane & 15) * 8;

  f32x4 acc[8];
#pragma unroll
  for (int i = 0; i < 8; ++i) acc[i] = (f32x4){0.f, 0.f, 0.f, 0.f};

  bf16x8 aS[4];
  bf16x8 bS[2][8];

  auto loadA = [&](int ks, bf16x8& d) {
    d = *reinterpret_cast<const bf16x8*>(apb + (size_t)ks * 512);
  };
  auto loadB = [&](int ks, bf16x8 (&d)[8]) {
    const short* p = bpb + (size_t)ks * 4096;
#pragma unroll
    for (int ct = 0; ct < 8; ++ct)
      d[ct] = *reinterpret_cast<const bf16x8*>(p + ct * 128);
  };
  auto step = [&](bf16x8& af, bf16x8 (&sb)[8]) {
    __builtin_amdgcn_s_setprio(1);
#pragma unroll
    for (int ct = 0; ct < 8; ++ct)
      acc[ct] = __builtin_amdgcn_mfma_f32_16x16x32_bf16(af, sb[ct], acc[ct], 0, 0, 0);
    __builtin_amdgcn_s_setprio(0);
  };

  loadA(0, aS[0]); loadA(1, aS[1]); loadA(2, aS[2]); loadA(3, aS[3]);
  loadB(0, bS[0]); loadB(1, bS[1]);
#pragma unroll
  for (int ks = 0; ks < 32; ++ks) {
    step(aS[ks & 3], bS[ks & 1]);
    if (ks + 4 < 32) loadA(ks + 4, aS[ks & 3]);
    if (ks + 2 < 32) loadB(ks + 2, bS[ks & 1]);
  }

  // ---- cross-wave K reduction + fused epilogue ----
  const int col = lane & 15, rq = lane >> 4;
  if (khalf == 1) {
#pragma unroll
    for (int reg = 0; reg < 4; ++reg)
#pragma unroll
      for (int ct = 0; ct < 8; ++ct)
        Red[strip][rq * 4 + reg][ct * 16 + col] = acc[ct][reg];
  }
  __syncthreads();
  if (khalf == 0) {
    const float* xr = xwsr + ((size_t)b * NN + rowb) * FD;
    float* ob = out + ((size_t)b * NN + rowb) * FD;
#pragma unroll
    for (int reg = 0; reg < 4; ++reg) {
      const int rloc = rq * 4 + reg;
      const float rn = r[b * NN + rowb + rloc];
#pragma unroll
      for (int ct = 0; ct < 8; ++ct) {
        const int o = ct * 16 + col;
        float v = acc[ct][reg] + Red[strip][rloc][o] + xr[(size_t)rloc * FD + o];
        v = rn * v + bias[o];
        ob[(size_t)rloc * FD + o] = v > 0.f ? v : 0.01f * v;
      }
    }
  }
}

extern "C" void kernel_launch(void* const* d_in, const int* in_sizes, int n_in,
                              void* d_out, int out_size, void* d_ws, size_t ws_size,
                              hipStream_t stream) {
  (void)in_sizes; (void)n_in; (void)out_size; (void)ws_size;
  const float* X    = (const float*)d_in[0];
  const float* adj  = (const float*)d_in[1];
  const float* W    = (const float*)d_in[2];
  const float* bias = (const float*)d_in[3];
  float* out = (float*)d_out;

  char* ws = (char*)d_ws;
  float* r     = (float*)ws;                       // 64 KB
  short* bpack = (short*)(ws + 65536);             // 4 MB
  float* xwsr  = (float*)(ws + 4259840);           // 8 MB
  short* apack = (short*)(ws + 12648448);          // 64 MB bf16 packed adj

  k_degpack<<<dim3(BB * NN / 16), dim3(256), 0, stream>>>(adj, apack, r);
  k_xw<<<dim3(NN / 64, BB), dim3(256), 0, stream>>>(X, W, r, bpack, xwsr);
  k_gemm3<<<dim3(NN / 32, BB), dim3(256), 0, stream>>>(apack, bpack, xwsr, r, bias, out);
}

// Round 5
// 75.266 us; speedup vs baseline: 1.2470x; 1.0145x over previous
//
#include <hip/hip_runtime.h>
#include <hip/hip_bf16.h>

#define BB 8
#define NN 2048
#define FD 128

typedef float f32x4 __attribute__((ext_vector_type(4)));
typedef short bf16x8 __attribute__((ext_vector_type(8)));
typedef short s16x4 __attribute__((ext_vector_type(4)));

__device__ __forceinline__ short f2bf(float f) {
  union { __hip_bfloat16 h; short s; } u;
  u.h = __float2bfloat16(f);
  return u.s;
}

// ---------------- kernel 1: r = rsqrt(1 + rowsum(adj)) ----------------
// Pure 134 MB streaming read at full occupancy (8 blocks/CU, 32 waves/CU).
__global__ __launch_bounds__(256) void k_degree(const float* __restrict__ adj,
                                                float* __restrict__ r) {
  const int row  = blockIdx.x * 4 + (threadIdx.x >> 6);
  const int lane = threadIdx.x & 63;
  const f32x4* p = reinterpret_cast<const f32x4*>(adj + (size_t)row * NN);
  float s = 0.f;
#pragma unroll
  for (int i = 0; i < 8; ++i) {
    f32x4 v = p[lane + 64 * i];
    s += (v.x + v.y) + (v.z + v.w);
  }
#pragma unroll
  for (int off = 32; off >= 1; off >>= 1) s += __shfl_xor(s, off, 64);
  if (lane == 0) r[row] = rsqrtf(1.0f + s);
}

// ---------------- kernel 2: XWs = r[m] * (X @ W), pack B-fragments ----------
// bpack: elem (m,o) -> (m>>3)*1024 + o*8 + (m&7); xwsr fp32 row-major.
__global__ __launch_bounds__(256) void k_xw(const float* __restrict__ X,
                                            const float* __restrict__ W,
                                            const float* __restrict__ r,
                                            short* __restrict__ bpack,
                                            float* __restrict__ xwsr) {
  __shared__ __align__(16) float Xs[64][132];
  __shared__ __align__(16) float Ws[128][128];
  const int b  = blockIdx.y;
  const int m0 = blockIdx.x * 64;
  const int t  = threadIdx.x;
  {
    const f32x4* wp = reinterpret_cast<const f32x4*>(W);
    f32x4* wd = reinterpret_cast<f32x4*>(&Ws[0][0]);
#pragma unroll
    for (int i = 0; i < 16; ++i) wd[t + 256 * i] = wp[t + 256 * i];
    const f32x4* xp = reinterpret_cast<const f32x4*>(X + ((size_t)b * NN + m0) * FD);
#pragma unroll
    for (int i = 0; i < 8; ++i) {
      int slot = t + 256 * i;
      f32x4 v = xp[slot];
      *reinterpret_cast<f32x4*>(&Xs[slot >> 5][(slot & 31) * 4]) = v;
    }
  }
  __syncthreads();
  const int ot = (t & 15) * 8;
  const int mt = (t >> 4) * 4;
  float acc[4][8];
#pragma unroll
  for (int i = 0; i < 4; ++i)
#pragma unroll
    for (int j = 0; j < 8; ++j) acc[i][j] = 0.f;

  for (int k = 0; k < 128; k += 4) {
    f32x4 xv[4];
#pragma unroll
    for (int i = 0; i < 4; ++i) xv[i] = *reinterpret_cast<const f32x4*>(&Xs[mt + i][k]);
#pragma unroll
    for (int kk = 0; kk < 4; ++kk) {
      float wv[8];
#pragma unroll
      for (int j = 0; j < 8; ++j) wv[j] = Ws[k + kk][ot + j];
#pragma unroll
      for (int i = 0; i < 4; ++i)
#pragma unroll
        for (int j = 0; j < 8; ++j) acc[i][j] = fmaf(xv[i][kk], wv[j], acc[i][j]);
    }
  }
  const int bm = b * NN + m0 + mt;
#pragma unroll
  for (int i = 0; i < 4; ++i) {
    float rm = r[bm + i];
#pragma unroll
    for (int j = 0; j < 8; ++j) acc[i][j] *= rm;
  }
#pragma unroll
  for (int i = 0; i < 4; ++i) {
    f32x4 lo = {acc[i][0], acc[i][1], acc[i][2], acc[i][3]};
    f32x4 hi = {acc[i][4], acc[i][5], acc[i][6], acc[i][7]};
    float* dst = xwsr + (size_t)(bm + i) * FD + ot;
    *reinterpret_cast<f32x4*>(dst) = lo;
    *reinterpret_cast<f32x4*>(dst + 4) = hi;
  }
  short* bp = bpack + (size_t)b * NN * FD;
  const int grp = (m0 + mt) >> 3;
  const int h   = ((m0 + mt) >> 2) & 1;
#pragma unroll
  for (int j = 0; j < 8; ++j) {
    s16x4 sv;
#pragma unroll
    for (int i = 0; i < 4; ++i) sv[i] = f2bf(acc[i][j]);
    *reinterpret_cast<s16x4*>(bp + (size_t)grp * 1024 + (ot + j) * 8 + h * 4) = sv;
  }
}

// ---------------- kernel 3: LDS-free MFMA GEMM, K-split waves ----------------
// out = leaky(r[n] * ((adj @ XWs) + XWs[n]) + bias)
// Block = 32 rows, 4 waves: (strip = w&1, khalf = w>>1). A-frags direct from
// L3-warm fp32 adj (cvt to bf16 in-reg), 4-deep prefetch; B-frags from L2
// bpack, 2-deep. khalf=1 partials reduced into khalf=0 via padded LDS.
__global__ __launch_bounds__(256) void k_gemm2(const float* __restrict__ adj,
                                               const short* __restrict__ bpack,
                                               const float* __restrict__ xwsr,
                                               const float* __restrict__ r,
                                               const float* __restrict__ bias,
                                               float* __restrict__ out) {
  __shared__ float Red[2][16][132];
  const int b     = blockIdx.y;
  const int n0    = blockIdx.x * 32;
  const int t     = threadIdx.x;
  const int lane  = t & 63;
  const int w     = t >> 6;
  const int strip = w & 1;
  const int khalf = w >> 1;
  const int rowb  = n0 + strip * 16;

  const float* ap  = adj + ((size_t)b * NN + rowb + (lane & 15)) * NN + khalf * 1024 + (lane >> 4) * 8;
  const short* bpb = bpack + (size_t)b * NN * FD + (size_t)(khalf * 128 + (lane >> 4)) * 1024 + (lane & 15) * 8;

  f32x4 acc[8];
#pragma unroll
  for (int i = 0; i < 8; ++i) acc[i] = (f32x4){0.f, 0.f, 0.f, 0.f};

  f32x4 aS[4][2];
  bf16x8 bS[2][8];

  auto loadA = [&](int ks, f32x4 (&d)[2]) {
    const f32x4* q = reinterpret_cast<const f32x4*>(ap + ks * 32);
    d[0] = q[0];
    d[1] = q[1];
  };
  auto loadB = [&](int ks, bf16x8 (&d)[8]) {
    const short* p = bpb + (size_t)ks * 4096;
#pragma unroll
    for (int ct = 0; ct < 8; ++ct)
      d[ct] = *reinterpret_cast<const bf16x8*>(p + ct * 128);
  };
  auto step = [&](f32x4 (&sa)[2], bf16x8 (&sb)[8]) {
    bf16x8 af;
#pragma unroll
    for (int i = 0; i < 4; ++i) { af[i] = f2bf(sa[0][i]); af[4 + i] = f2bf(sa[1][i]); }
    __builtin_amdgcn_s_setprio(1);
#pragma unroll
    for (int ct = 0; ct < 8; ++ct)
      acc[ct] = __builtin_amdgcn_mfma_f32_16x16x32_bf16(af, sb[ct], acc[ct], 0, 0, 0);
    __builtin_amdgcn_s_setprio(0);
  };

  loadA(0, aS[0]); loadA(1, aS[1]); loadA(2, aS[2]); loadA(3, aS[3]);
  loadB(0, bS[0]); loadB(1, bS[1]);
#pragma unroll
  for (int ks = 0; ks < 32; ++ks) {
    step(aS[ks & 3], bS[ks & 1]);
    if (ks + 4 < 32) loadA(ks + 4, aS[ks & 3]);
    if (ks + 2 < 32) loadB(ks + 2, bS[ks & 1]);
  }

  // ---- cross-wave K reduction + fused epilogue ----
  // C/D layout: col = lane&15, row = (lane>>4)*4 + reg
  const int col = lane & 15, rq = lane >> 4;
  if (khalf == 1) {
#pragma unroll
    for (int reg = 0; reg < 4; ++reg)
#pragma unroll
      for (int ct = 0; ct < 8; ++ct)
        Red[strip][rq * 4 + reg][ct * 16 + col] = acc[ct][reg];
  }
  __syncthreads();
  if (khalf == 0) {
    const float* xr = xwsr + ((size_t)b * NN + rowb) * FD;
    float* ob = out + ((size_t)b * NN + rowb) * FD;
#pragma unroll
    for (int reg = 0; reg < 4; ++reg) {
      const int rloc = rq * 4 + reg;
      const float rn = r[b * NN + rowb + rloc];
#pragma unroll
      for (int ct = 0; ct < 8; ++ct) {
        const int o = ct * 16 + col;
        float v = acc[ct][reg] + Red[strip][rloc][o] + xr[(size_t)rloc * FD + o];
        v = rn * v + bias[o];
        ob[(size_t)rloc * FD + o] = v > 0.f ? v : 0.01f * v;
      }
    }
  }
}

extern "C" void kernel_launch(void* const* d_in, const int* in_sizes, int n_in,
                              void* d_out, int out_size, void* d_ws, size_t ws_size,
                              hipStream_t stream) {
  (void)in_sizes; (void)n_in; (void)out_size; (void)ws_size;
  const float* X    = (const float*)d_in[0];
  const float* adj  = (const float*)d_in[1];
  const float* W    = (const float*)d_in[2];
  const float* bias = (const float*)d_in[3];
  float* out = (float*)d_out;

  char* ws = (char*)d_ws;
  float* r     = (float*)ws;                       // 64 KB
  short* bpack = (short*)(ws + 65536);             // 4 MB
  float* xwsr  = (float*)(ws + 4259840);           // 8 MB

  k_degree<<<dim3(BB * NN / 4), dim3(256), 0, stream>>>(adj, r);
  k_xw<<<dim3(NN / 64, BB), dim3(256), 0, stream>>>(X, W, r, bpack, xwsr);
  k_gemm2<<<dim3(NN / 32, BB), dim3(256), 0, stream>>>(adj, bpack, xwsr, r, bias, out);
}